// Round 2
// baseline (128.591 us; speedup 1.0000x reference)
//
#include <hip/hip_runtime.h>
#include <math.h>

// Problem constants (StructureLoss: B=32, C=1, H=W=512, 31x31 box filter, pad 15)
#define BB 32
#define HH 512
#define WW 512
#define KK 31
#define PP 15
#define HSEG 8                        // rows per block segment (all staged per barrier)
#define BLOCKS_PER_IMG (HH / HSEG)    // 64
#define NBLOCKS (BB * BLOCKS_PER_IMG) // 2048  -> 8 blocks/CU, 32 waves/CU
#define NTHREADS 256                  // 2 adjacent columns per thread (float2 lanes)
#define W2 (WW / 2)                   // 256 float2 per row
#define HALO2 8                       // float2 halo each side (covers +/-15 floats)
#define LROW (W2 + 2 * HALO2)         // 272 float2 per LDS row

__device__ inline float wave_reduce(float v) {
    #pragma unroll
    for (int off = 32; off > 0; off >>= 1) v += __shfl_down(v, off);
    return v;
}

__device__ inline void accum_px(float s, float tg, float x,
                                float& aw, float& ab, float& ai, float& au) {
    const float inv = 1.0f / (float)(KK * KK);
    float pooled = s * inv;
    float weit = fmaf(5.0f, fabsf(pooled - tg), 1.0f);
    // stable BCE-with-logits, elementwise
    float bce = fmaxf(x, 0.0f) - x * tg + __logf(1.0f + __expf(-fabsf(x)));
    float p = 1.0f / (1.0f + __expf(-x));
    aw += weit;
    ab += weit * bce;
    ai += p * tg * weit;
    au += (p + tg) * weit;
}

__global__ __launch_bounds__(NTHREADS, 8) void structure_loss_main(
    const float* __restrict__ pred, const float* __restrict__ target,
    float* __restrict__ partials /* [NBLOCKS][4] */)
{
    __shared__ float2 svs[HSEG][LROW];   // HSEG rows of vertical sums + zero halos
    __shared__ float red[4 * 4];         // [wave][quantity]

    const int t   = threadIdx.x;
    const int blk = blockIdx.x;
    const int b   = blk / BLOCKS_PER_IMG;
    const int seg = blk % BLOCKS_PER_IMG;
    const int h0  = seg * HSEG;
    const int c0  = 2 * t;

    const float* tb = target + (size_t)b * HH * WW;
    const float* pb = pred   + (size_t)b * HH * WW;

    // zero the horizontal halos (written once, before the single barrier)
    if (t < HALO2) {
        #pragma unroll
        for (int r = 0; r < HSEG; ++r) {
            svs[r][t]              = make_float2(0.0f, 0.0f);
            svs[r][HALO2 + W2 + t] = make_float2(0.0f, 0.0f);
        }
    }

    // initial vertical window for output row h0: rows [h0-PP, h0+PP] clipped
    float vs0 = 0.0f, vs1 = 0.0f;
    {
        int ylo = h0 - PP; if (ylo < 0) ylo = 0;
        int yhi = h0 + PP; if (yhi > HH - 1) yhi = HH - 1;
        for (int y = ylo; y <= yhi; ++y) {
            float2 v = *(const float2*)(tb + (size_t)y * WW + c0);
            vs0 += v.x; vs1 += v.y;
        }
    }

    // stage all HSEG rows of vertical sums, sliding the window between rows
    #pragma unroll
    for (int r = 0; r < HSEG; ++r) {
        svs[r][HALO2 + t] = make_float2(vs0, vs1);
        int h = h0 + r;
        int yadd = h + PP + 1;      // uniform per block-row -> uniform branch
        int ysub = h - PP;
        if (yadd < HH) {
            float2 v = *(const float2*)(tb + (size_t)yadd * WW + c0);
            vs0 += v.x; vs1 += v.y;
        }
        if (ysub >= 0) {
            float2 v = *(const float2*)(tb + (size_t)ysub * WW + c0);
            vs0 -= v.x; vs1 -= v.y;
        }
    }

    __syncthreads();   // the ONLY data barrier

    float aw = 0.0f, ab = 0.0f, ai = 0.0f, au = 0.0f;

    #pragma unroll 2
    for (int r = 0; r < HSEG; ++r) {
        const int h = h0 + r;
        float2 tg = *(const float2*)(tb + (size_t)h * WW + c0);
        float2 pr = *(const float2*)(pb + (size_t)h * WW + c0);

        // 17 conflict-free b64 taps covering floats [c0-16, c0+17]
        float2 v0  = svs[r][t];        // floats c0-16 (x), c0-15 (y)
        float2 v16 = svs[r][t + 16];   // floats c0+16 (x), c0+17 (y)
        float sx = v0.x + v16.x;
        float sy = v0.y + v16.y;
        #pragma unroll
        for (int j = 1; j < 16; ++j) {
            float2 v = svs[r][t + j];
            sx += v.x; sy += v.y;
        }
        // s0 = sum floats [c0-15, c0+15]; s1 = sum floats [c0-14, c0+16]
        float s0 = (sx - v0.x - v16.x) + (sy - v16.y);
        float s1 = s0 - v0.y + v16.x;

        accum_px(s0, tg.x, pr.x, aw, ab, ai, au);
        accum_px(s1, tg.y, pr.y, aw, ab, ai, au);
    }

    // block reduction: wave shuffle, then across the 4 waves via LDS
    aw = wave_reduce(aw);
    ab = wave_reduce(ab);
    ai = wave_reduce(ai);
    au = wave_reduce(au);

    const int wave = t >> 6;
    const int lane = t & 63;
    __syncthreads();
    if (lane == 0) {
        red[wave * 4 + 0] = aw;
        red[wave * 4 + 1] = ab;
        red[wave * 4 + 2] = ai;
        red[wave * 4 + 3] = au;
    }
    __syncthreads();
    if (t == 0) {
        float w = 0.0f, bc = 0.0f, in = 0.0f, un = 0.0f;
        #pragma unroll
        for (int i = 0; i < 4; ++i) {
            w  += red[i * 4 + 0];
            bc += red[i * 4 + 1];
            in += red[i * 4 + 2];
            un += red[i * 4 + 3];
        }
        float* o = partials + (size_t)blk * 4;
        o[0] = w; o[1] = bc; o[2] = in; o[3] = un;
    }
}

__global__ __launch_bounds__(64) void structure_loss_finalize(
    const float* __restrict__ partials, float* __restrict__ out)
{
    const int b = threadIdx.x;
    float val = 0.0f;
    if (b < BB) {
        float w = 0.0f, bc = 0.0f, in = 0.0f, un = 0.0f;
        for (int i = 0; i < BLOCKS_PER_IMG; ++i) {
            const float* p = partials + ((size_t)(b * BLOCKS_PER_IMG + i)) * 4;
            w  += p[0];
            bc += p[1];
            in += p[2];
            un += p[3];
        }
        float wbce = bc / w;
        float wiou = 1.0f - (in + 1.0f) / (un - in + 1.0f);
        val = wbce + wiou;
    }
    val = wave_reduce(val);
    if (b == 0) out[0] = val / (float)BB;
}

extern "C" void kernel_launch(void* const* d_in, const int* in_sizes, int n_in,
                              void* d_out, int out_size, void* d_ws, size_t ws_size,
                              hipStream_t stream) {
    const float* pred   = (const float*)d_in[0];
    const float* target = (const float*)d_in[1];
    float* out      = (float*)d_out;
    float* partials = (float*)d_ws;   // NBLOCKS*4 floats = 32 KB

    structure_loss_main<<<NBLOCKS, NTHREADS, 0, stream>>>(pred, target, partials);
    structure_loss_finalize<<<1, 64, 0, stream>>>(partials, out);
}

// Round 3
// 114.031 us; speedup vs baseline: 1.1277x; 1.1277x over previous
//
#include <hip/hip_runtime.h>
#include <math.h>

// StructureLoss: B=32, C=1, H=W=512, 31x31 box filter, pad 15
#define BB 32
#define HH 512
#define WW 512
#define KK 31
#define PP 15
#define HSEG 16                       // rows per block (low vertical-halo refetch)
#define BLOCKS_PER_IMG (HH / HSEG)    // 32
#define NBLOCKS (BB * BLOCKS_PER_IMG) // 1024 -> 4 blocks/CU
#define NTHREADS 256                  // 2 adjacent columns per thread
#define W2 (WW / 2)                   // 256 float2 per row
#define HALO2 8                       // float2 halo each side (covers +/-15 floats)
#define LROW (W2 + 2 * HALO2)         // 272 float2 per LDS row

__device__ inline float wave_reduce(float v) {
    #pragma unroll
    for (int off = 32; off > 0; off >>= 1) v += __shfl_down(v, off);
    return v;
}

// 3 transcendentals/px: e=exp(-|x|), r=rcp(1+e) -> sigmoid = r or 1-r,
// log1p(e) = -log(r)
__device__ inline void accum_px(float s, float tg, float x,
                                float& aw, float& ab, float& ai, float& au) {
    const float inv = 1.0f / (float)(KK * KK);
    float pooled = s * inv;
    float weit = fmaf(5.0f, fabsf(pooled - tg), 1.0f);
    float e  = __expf(-fabsf(x));
    float rr = __builtin_amdgcn_rcpf(1.0f + e);
    float bce = fmaxf(x, 0.0f) - x * tg - __logf(rr);
    float p  = (x >= 0.0f) ? rr : (1.0f - rr);
    aw += weit;
    ab = fmaf(weit, bce, ab);
    ai = fmaf(p * tg, weit, ai);
    au = fmaf(p + tg, weit, au);
}

__device__ inline float2 ld2(const float* base, int y, int c0) {
    return *(const float2*)(base + (size_t)y * WW + c0);
}

__global__ __launch_bounds__(NTHREADS, 4) void structure_loss_main(
    const float* __restrict__ pred, const float* __restrict__ target,
    float* __restrict__ partials /* [NBLOCKS][4] */)
{
    __shared__ float2 svs[3][LROW];   // triple-buffered rows of vertical sums
    __shared__ float red[4 * 4];

    const int t   = threadIdx.x;
    const int blk = blockIdx.x;
    const int b   = blk / BLOCKS_PER_IMG;
    const int seg = blk % BLOCKS_PER_IMG;
    const int h0  = seg * HSEG;
    const int c0  = 2 * t;

    const float* tb = target + (size_t)b * HH * WW;
    const float* pb = pred   + (size_t)b * HH * WW;

    // zero the horizontal halos of all 3 buffers (written once, pre-first-barrier)
    if (t < HALO2) {
        #pragma unroll
        for (int q = 0; q < 3; ++q) {
            svs[q][t]              = make_float2(0.0f, 0.0f);
            svs[q][HALO2 + W2 + t] = make_float2(0.0f, 0.0f);
        }
    }

    // initial vertical window for output row h0: rows [h0-PP, h0+PP] clipped
    float vs0 = 0.0f, vs1 = 0.0f;
    {
        int ylo = h0 - PP; if (ylo < 0) ylo = 0;
        int yhi = h0 + PP; if (yhi > HH - 1) yhi = HH - 1;
        for (int y = ylo; y <= yhi; ++y) {
            float2 v = ld2(tb, y, c0);
            vs0 += v.x; vs1 += v.y;
        }
    }
    svs[0][HALO2 + t] = make_float2(vs0, vs1);   // row h0 -> buf 0

    // prologue prefetch: consumables for epoch 0
    float2 tgc = ld2(tb, h0, c0);
    float2 prc = ld2(pb, h0, c0);
    // slide rows for staging row 1 at epoch 0: add h0+16, sub h0-15
    float2 va = (h0 + 16 < HH) ? ld2(tb, h0 + 16, c0) : make_float2(0.f, 0.f);
    float2 vb = (h0 - 15 >= 0) ? ld2(tb, h0 - 15, c0) : make_float2(0.f, 0.f);

    float aw = 0.0f, ab = 0.0f, ai = 0.0f, au = 0.0f;

    // rotating buffer pointers: read <- r%3, write <- (r+1)%3
    float2* p_read  = svs[0];
    float2* p_write = svs[1];
    float2* p_spare = svs[2];

    for (int r = 0; r < HSEG; ++r) {
        // stage row r+1 (uses va/vb prefetched one epoch ago)
        if (r < HSEG - 1) {
            vs0 += va.x - vb.x;
            vs1 += va.y - vb.y;
            p_write[HALO2 + t] = make_float2(vs0, vs1);
        }
        __syncthreads();   // one barrier per row

        // prefetch for epoch r+1 (issued before the LDS/VALU consume work)
        float2 van = make_float2(0.f, 0.f), vbn = make_float2(0.f, 0.f);
        float2 tgn = make_float2(0.f, 0.f), prn = make_float2(0.f, 0.f);
        if (r < HSEG - 1) {
            int ha = h0 + r + 17;   // add-row for slide r+1 -> r+2
            int hs = h0 + r - 14;   // sub-row
            if (ha < HH)  van = ld2(tb, ha, c0);
            if (hs >= 0)  vbn = ld2(tb, hs, c0);
            tgn = ld2(tb, h0 + r + 1, c0);
            prn = ld2(pb, h0 + r + 1, c0);
        }

        // consume row r: 17 b64 taps covering floats [c0-16, c0+17]
        float2 v0  = p_read[t];
        float2 v16 = p_read[t + 16];
        float sx = v0.x + v16.x;
        float sy = v0.y + v16.y;
        #pragma unroll
        for (int j = 1; j < 16; ++j) {
            float2 v = p_read[t + j];
            sx += v.x; sy += v.y;
        }
        float s0 = (sx - v0.x - v16.x) + (sy - v16.y);  // cols [c0-15, c0+15]
        float s1 = s0 - v0.y + v16.x;                   // cols [c0-14, c0+16]

        accum_px(s0, tgc.x, prc.x, aw, ab, ai, au);
        accum_px(s1, tgc.y, prc.y, aw, ab, ai, au);

        // rotate state for next epoch
        tgc = tgn; prc = prn; va = van; vb = vbn;
        float2* tmp = p_read;
        p_read  = p_write;
        p_write = p_spare;
        p_spare = tmp;
    }

    // block reduction: wave shuffle, then across the 4 waves via LDS
    aw = wave_reduce(aw);
    ab = wave_reduce(ab);
    ai = wave_reduce(ai);
    au = wave_reduce(au);

    const int wave = t >> 6;
    const int lane = t & 63;
    __syncthreads();
    if (lane == 0) {
        red[wave * 4 + 0] = aw;
        red[wave * 4 + 1] = ab;
        red[wave * 4 + 2] = ai;
        red[wave * 4 + 3] = au;
    }
    __syncthreads();
    if (t == 0) {
        float w = 0.0f, bc = 0.0f, in = 0.0f, un = 0.0f;
        #pragma unroll
        for (int i = 0; i < 4; ++i) {
            w  += red[i * 4 + 0];
            bc += red[i * 4 + 1];
            in += red[i * 4 + 2];
            un += red[i * 4 + 3];
        }
        float* o = partials + (size_t)blk * 4;
        o[0] = w; o[1] = bc; o[2] = in; o[3] = un;
    }
}

__global__ __launch_bounds__(64) void structure_loss_finalize(
    const float* __restrict__ partials, float* __restrict__ out)
{
    const int b = threadIdx.x;
    float val = 0.0f;
    if (b < BB) {
        float w = 0.0f, bc = 0.0f, in = 0.0f, un = 0.0f;
        for (int i = 0; i < BLOCKS_PER_IMG; ++i) {
            const float* p = partials + ((size_t)(b * BLOCKS_PER_IMG + i)) * 4;
            w  += p[0];
            bc += p[1];
            in += p[2];
            un += p[3];
        }
        float wbce = bc / w;
        float wiou = 1.0f - (in + 1.0f) / (un - in + 1.0f);
        val = wbce + wiou;
    }
    val = wave_reduce(val);
    if (b == 0) out[0] = val / (float)BB;
}

extern "C" void kernel_launch(void* const* d_in, const int* in_sizes, int n_in,
                              void* d_out, int out_size, void* d_ws, size_t ws_size,
                              hipStream_t stream) {
    const float* pred   = (const float*)d_in[0];
    const float* target = (const float*)d_in[1];
    float* out      = (float*)d_out;
    float* partials = (float*)d_ws;   // NBLOCKS*4 floats = 16 KB

    structure_loss_main<<<NBLOCKS, NTHREADS, 0, stream>>>(pred, target, partials);
    structure_loss_finalize<<<1, 64, 0, stream>>>(partials, out);
}

// Round 4
// 113.914 us; speedup vs baseline: 1.1288x; 1.0010x over previous
//
#include <hip/hip_runtime.h>
#include <math.h>

// StructureLoss: B=32, C=1, H=W=512, 31x31 box filter, pad 15
#define BB 32
#define HH 512
#define WW 512
#define KK 31
#define PP 15
#define HSEG 16                       // rows per block (low vertical-halo refetch)
#define BLOCKS_PER_IMG (HH / HSEG)    // 32
#define NBLOCKS (BB * BLOCKS_PER_IMG) // 1024 -> 4 blocks/CU
#define NTHREADS 256                  // 2 adjacent columns per thread
#define W2 (WW / 2)                   // 256 float2 per row
#define HALO2 8                       // float2 halo each side (covers +/-15 floats)
#define LROW (W2 + 2 * HALO2)         // 272 float2 per LDS row

__device__ inline float wave_reduce(float v) {
    #pragma unroll
    for (int off = 32; off > 0; off >>= 1) v += __shfl_down(v, off);
    return v;
}

// 3 transcendentals/px: e=exp(-|x|), r=rcp(1+e) -> sigmoid = r or 1-r,
// log1p(e) = -log(r)
__device__ inline void accum_px(float s, float tg, float x,
                                float& aw, float& ab, float& ai, float& au) {
    const float inv = 1.0f / (float)(KK * KK);
    float pooled = s * inv;
    float weit = fmaf(5.0f, fabsf(pooled - tg), 1.0f);
    float e  = __expf(-fabsf(x));
    float rr = __builtin_amdgcn_rcpf(1.0f + e);
    float bce = fmaxf(x, 0.0f) - x * tg - __logf(rr);
    float p  = (x >= 0.0f) ? rr : (1.0f - rr);
    aw += weit;
    ab = fmaf(weit, bce, ab);
    ai = fmaf(p * tg, weit, ai);
    au = fmaf(p + tg, weit, au);
}

__device__ inline float2 ld2(const float* base, int y, int c0) {
    return *(const float2*)(base + (size_t)y * WW + c0);
}

__global__ __launch_bounds__(NTHREADS, 4) void structure_loss_main(
    const float* __restrict__ pred, const float* __restrict__ target,
    float* __restrict__ partials /* [NBLOCKS][4] */)
{
    __shared__ float2 svs[3][LROW];   // triple-buffered rows of vertical sums
    __shared__ float red[4 * 4];

    const int t   = threadIdx.x;
    const int blk = blockIdx.x;
    const int b   = blk / BLOCKS_PER_IMG;
    const int seg = blk % BLOCKS_PER_IMG;
    const int h0  = seg * HSEG;
    const int c0  = 2 * t;

    const float* tb = target + (size_t)b * HH * WW;
    const float* pb = pred   + (size_t)b * HH * WW;

    // zero the horizontal halos of all 3 buffers (written once, pre-first-barrier)
    if (t < HALO2) {
        #pragma unroll
        for (int q = 0; q < 3; ++q) {
            svs[q][t]              = make_float2(0.0f, 0.0f);
            svs[q][HALO2 + W2 + t] = make_float2(0.0f, 0.0f);
        }
    }

    // ---- initial vertical window for row h0: rows [h0-PP, h0+PP] ----
    // STATIC 31-iteration loop (unrollable -> all loads in flight at once).
    float vs0 = 0.0f, vs1 = 0.0f;
    if (seg > 0 && seg < BLOCKS_PER_IMG - 1) {
        // interior: all 31 rows valid, no clamping at all
        #pragma unroll
        for (int j = -PP; j <= PP; ++j) {
            float2 v = ld2(tb, h0 + j, c0);
            vs0 += v.x; vs1 += v.y;
        }
    } else {
        #pragma unroll
        for (int j = -PP; j <= PP; ++j) {
            int y  = h0 + j;
            int yc = min(max(y, 0), HH - 1);
            float2 v = ld2(tb, yc, c0);
            bool ok = (y >= 0) && (y < HH);
            vs0 += ok ? v.x : 0.0f;
            vs1 += ok ? v.y : 0.0f;
        }
    }
    svs[0][HALO2 + t] = make_float2(vs0, vs1);   // row h0 -> buf 0

    // prologue prefetch for epoch 0
    float2 tgc = ld2(tb, h0, c0);
    float2 prc = ld2(pb, h0, c0);
    float2 va, vb;     // slide rows for staging row 1: add h0+16, sub h0-15
    {
        int ha = h0 + 16, hs = h0 - 15;
        float2 a2 = ld2(tb, min(ha, HH - 1), c0);
        float2 b2 = ld2(tb, max(hs, 0), c0);
        va = (ha < HH) ? a2 : make_float2(0.f, 0.f);
        vb = (hs >= 0) ? b2 : make_float2(0.f, 0.f);
    }

    float aw = 0.0f, ab = 0.0f, ai = 0.0f, au = 0.0f;

    #pragma unroll
    for (int r = 0; r < HSEG; ++r) {
        // stage row r+1 into buf (r+1)%3 (va/vb prefetched one epoch ago)
        if (r < HSEG - 1) {
            vs0 += va.x - vb.x;
            vs1 += va.y - vb.y;
            svs[(r + 1) % 3][HALO2 + t] = make_float2(vs0, vs1);
        }
        __syncthreads();   // one barrier per row; triple buffer makes this safe

        // prefetch for epoch r+1 (issued before the LDS/VALU consume work)
        float2 van = make_float2(0.f, 0.f), vbn = make_float2(0.f, 0.f);
        float2 tgn = make_float2(0.f, 0.f), prn = make_float2(0.f, 0.f);
        if (r < HSEG - 1) {                 // compile-time after unroll
            tgn = ld2(tb, h0 + r + 1, c0);
            prn = ld2(pb, h0 + r + 1, c0);
        }
        if (r < HSEG - 2) {                 // slide rows for staging row r+2
            int ha = h0 + r + 17;
            int hs = h0 + r - 14;
            float2 a2 = ld2(tb, min(ha, HH - 1), c0);
            float2 b2 = ld2(tb, max(hs, 0), c0);
            van = (ha < HH) ? a2 : make_float2(0.f, 0.f);
            vbn = (hs >= 0) ? b2 : make_float2(0.f, 0.f);
        }

        // consume row r from buf r%3: 17 b64 taps covering floats [c0-16, c0+17]
        float2 v0  = svs[r % 3][t];
        float2 v16 = svs[r % 3][t + 16];
        float sx = v0.x + v16.x;
        float sy = v0.y + v16.y;
        #pragma unroll
        for (int j = 1; j < 16; ++j) {
            float2 v = svs[r % 3][t + j];
            sx += v.x; sy += v.y;
        }
        float s0 = (sx - v0.x - v16.x) + (sy - v16.y);  // cols [c0-15, c0+15]
        float s1 = s0 - v0.y + v16.x;                   // cols [c0-14, c0+16]

        accum_px(s0, tgc.x, prc.x, aw, ab, ai, au);
        accum_px(s1, tgc.y, prc.y, aw, ab, ai, au);

        tgc = tgn; prc = prn; va = van; vb = vbn;
    }

    // block reduction: wave shuffle, then across the 4 waves via LDS
    aw = wave_reduce(aw);
    ab = wave_reduce(ab);
    ai = wave_reduce(ai);
    au = wave_reduce(au);

    const int wave = t >> 6;
    const int lane = t & 63;
    __syncthreads();
    if (lane == 0) {
        red[wave * 4 + 0] = aw;
        red[wave * 4 + 1] = ab;
        red[wave * 4 + 2] = ai;
        red[wave * 4 + 3] = au;
    }
    __syncthreads();
    if (t == 0) {
        float w = 0.0f, bc = 0.0f, in = 0.0f, un = 0.0f;
        #pragma unroll
        for (int i = 0; i < 4; ++i) {
            w  += red[i * 4 + 0];
            bc += red[i * 4 + 1];
            in += red[i * 4 + 2];
            un += red[i * 4 + 3];
        }
        float* o = partials + (size_t)blk * 4;
        o[0] = w; o[1] = bc; o[2] = in; o[3] = un;
    }
}

__global__ __launch_bounds__(256) void structure_loss_finalize(
    const float* __restrict__ partials, float* __restrict__ out)
{
    // partials: [1024][4]; image b owns entries [b*32, (b+1)*32)
    const int t  = threadIdx.x;      // 256 threads
    const int b  = t >> 3;           // image 0..31  (8 threads per image)
    const int i0 = (t & 7) * 4;      // 4 partial-entries per thread
    float w = 0.f, bc = 0.f, in = 0.f, un = 0.f;
    #pragma unroll
    for (int k = 0; k < 4; ++k) {
        float4 v = *(const float4*)(partials + ((size_t)(b * 32 + i0 + k)) * 4);
        w += v.x; bc += v.y; in += v.z; un += v.w;
    }
    // reduce within each 8-thread (same-image) group via shuffles
    #pragma unroll
    for (int off = 4; off > 0; off >>= 1) {
        w  += __shfl_down(w, off);
        bc += __shfl_down(bc, off);
        in += __shfl_down(in, off);
        un += __shfl_down(un, off);
    }
    __shared__ float vals[32];
    if ((t & 7) == 0) {
        float wbce = bc / w;
        float wiou = 1.0f - (in + 1.0f) / (un - in + 1.0f);
        vals[b] = wbce + wiou;
    }
    __syncthreads();
    if (t < 64) {
        float v = (t < 32) ? vals[t] : 0.0f;
        v = wave_reduce(v);
        if (t == 0) out[0] = v / (float)BB;
    }
}

extern "C" void kernel_launch(void* const* d_in, const int* in_sizes, int n_in,
                              void* d_out, int out_size, void* d_ws, size_t ws_size,
                              hipStream_t stream) {
    const float* pred   = (const float*)d_in[0];
    const float* target = (const float*)d_in[1];
    float* out      = (float*)d_out;
    float* partials = (float*)d_ws;   // NBLOCKS*4 floats = 16 KB

    structure_loss_main<<<NBLOCKS, NTHREADS, 0, stream>>>(pred, target, partials);
    structure_loss_finalize<<<1, 256, 0, stream>>>(partials, out);
}

// Round 5
// 112.157 us; speedup vs baseline: 1.1465x; 1.0157x over previous
//
#include <hip/hip_runtime.h>
#include <math.h>

// StructureLoss: B=32, C=1, H=W=512, 31x31 box filter, pad 15
#define BB 32
#define HH 512
#define WW 512
#define KK 31
#define PP 15
#define HSEG 16                       // rows per block
#define BLOCKS_PER_IMG (HH / HSEG)    // 32
#define NBLOCKS (BB * BLOCKS_PER_IMG) // 1024 -> 4 blocks/CU
#define NTHREADS 256                  // 2 row-groups x 128 threads x 4 cols
#define NEPOCH 8                      // rows per group
#define LF4 136                       // float4 per LDS row: 4 halo + 128 + 4 halo

__device__ inline float wave_reduce(float v) {
    #pragma unroll
    for (int off = 32; off > 0; off >>= 1) v += __shfl_down(v, off);
    return v;
}

// 3 transcendentals/px: e=exp(-|x|), r=rcp(1+e) -> sigmoid = r or 1-r,
// log1p(e) = -log(r)
__device__ inline void accum_px(float s, float tg, float x,
                                float& aw, float& ab, float& ai, float& au) {
    const float inv = 1.0f / (float)(KK * KK);
    float pooled = s * inv;
    float weit = fmaf(5.0f, fabsf(pooled - tg), 1.0f);
    float e  = __expf(-fabsf(x));
    float rr = __builtin_amdgcn_rcpf(1.0f + e);
    float bce = fmaxf(x, 0.0f) - x * tg - __logf(rr);
    float p  = (x >= 0.0f) ? rr : (1.0f - rr);
    aw += weit;
    ab = fmaf(weit, bce, ab);
    ai = fmaf(p * tg, weit, ai);
    au = fmaf(p + tg, weit, au);
}

__device__ inline float4 ld4(const float* base, int y, int c0) {
    return *(const float4*)(base + (size_t)y * WW + c0);
}
// row-clamped load, zeroed if row OOB (branch-free select; row index uniform)
__device__ inline float4 ld4z(const float* base, int y, int c0) {
    int yc = min(max(y, 0), HH - 1);
    float4 v = *(const float4*)(base + (size_t)yc * WW + c0);
    if (y < 0 || y >= HH) v = make_float4(0.f, 0.f, 0.f, 0.f);
    return v;
}

__global__ __launch_bounds__(NTHREADS, 4) void structure_loss_main(
    const float* __restrict__ pred, const float* __restrict__ target,
    float* __restrict__ partials /* [NBLOCKS][4] */)
{
    __shared__ float4 svs[2][2][LF4];   // [buf][group][4 halo + 128 + 4 halo]
    __shared__ float red[4 * 4];

    const int t   = threadIdx.x;
    const int grp = t >> 7;            // row-group 0/1 (wave-uniform)
    const int tl  = t & 127;
    const int c0  = 4 * tl;            // 4 columns per thread
    const int blk = blockIdx.x;
    const int b   = blk / BLOCKS_PER_IMG;
    const int seg = blk % BLOCKS_PER_IMG;
    const int hg  = seg * HSEG + NEPOCH * grp;   // group's first row

    const float* tb = target + (size_t)b * HH * WW;
    const float* pb = pred   + (size_t)b * HH * WW;

    // zero the 8 halo float4s of each of the 4 row buffers (written once)
    if (t < 32) {
        int buf = t >> 4, g = (t >> 3) & 1, i = t & 7;
        int idx = (i < 4) ? i : (LF4 - 8 + i);
        svs[buf][g][idx] = make_float4(0.f, 0.f, 0.f, 0.f);
    }

    // ---- initial vertical window for row hg: rows [hg-PP, hg+PP] ----
    float4 vs;
    {
        float vx = 0.f, vy = 0.f, vz = 0.f, vw = 0.f;
        if (hg >= PP && hg + PP < HH) {          // interior fast path (uniform)
            #pragma unroll
            for (int j = -PP; j <= PP; ++j) {
                float4 v = ld4(tb, hg + j, c0);
                vx += v.x; vy += v.y; vz += v.z; vw += v.w;
            }
        } else {
            #pragma unroll
            for (int j = -PP; j <= PP; ++j) {
                float4 v = ld4z(tb, hg + j, c0);
                vx += v.x; vy += v.y; vz += v.z; vw += v.w;
            }
        }
        vs = make_float4(vx, vy, vz, vw);
    }

    // prologue prefetch for epoch 0
    float4 tgc = ld4(tb, hg, c0);
    float4 prc = ld4(pb, hg, c0);
    float4 va  = ld4z(tb, hg + PP + 1, c0);   // add-row for slide hg -> hg+1
    float4 vb  = ld4z(tb, hg - PP, c0);       // sub-row

    float aw = 0.f, ab = 0.f, ai = 0.f, au = 0.f;

    #pragma unroll
    for (int e = 0; e < NEPOCH; ++e) {
        // stage this group's vertical-sum row into buffer e&1
        svs[e & 1][grp][4 + tl] = vs;
        __syncthreads();   // one barrier per epoch; double-buffer is race-free

        // prefetch for epoch e+1 (in flight across the consume phase)
        float4 tgn = make_float4(0.f,0.f,0.f,0.f), prn = tgn, van = tgn, vbn = tgn;
        if (e < NEPOCH - 1) {                 // compile-time after unroll
            int h = hg + e + 1;
            tgn = ld4(tb, h, c0);
            prn = ld4(pb, h, c0);
            van = ld4z(tb, h + PP + 1, c0);   // slide h+1 -> h+2
            vbn = ld4z(tb, h - PP, c0);
        }

        // consume row: 9 b128 taps covering floats [c0-16, c0+19]
        const float4* row = svs[e & 1][grp];
        float4 T0 = row[tl];            // floats c0-16 .. c0-13
        float4 T8 = row[tl + 8];        // floats c0+16 .. c0+19
        float S = T0.x + T0.y + T0.z + T0.w;
        #pragma unroll
        for (int k = 1; k < 8; ++k) {
            float4 v = row[tl + k];
            S += v.x + v.y + v.z + v.w;
        }
        // S = sum floats [c0-16, c0+15]
        float s0 = S  - T0.x;                  // cols [c0-15, c0+15]
        float s1 = s0 - T0.y + T8.x;           // col c0+1
        float s2 = s1 - T0.z + T8.y;           // col c0+2
        float s3 = s2 - T0.w + T8.z;           // col c0+3

        accum_px(s0, tgc.x, prc.x, aw, ab, ai, au);
        accum_px(s1, tgc.y, prc.y, aw, ab, ai, au);
        accum_px(s2, tgc.z, prc.z, aw, ab, ai, au);
        accum_px(s3, tgc.w, prc.w, aw, ab, ai, au);

        // slide vertical window to next row
        vs.x += va.x - vb.x;
        vs.y += va.y - vb.y;
        vs.z += va.z - vb.z;
        vs.w += va.w - vb.w;

        tgc = tgn; prc = prn; va = van; vb = vbn;
    }

    // block reduction: wave shuffle, then across the 4 waves via LDS
    aw = wave_reduce(aw);
    ab = wave_reduce(ab);
    ai = wave_reduce(ai);
    au = wave_reduce(au);

    const int wave = t >> 6;
    const int lane = t & 63;
    __syncthreads();
    if (lane == 0) {
        red[wave * 4 + 0] = aw;
        red[wave * 4 + 1] = ab;
        red[wave * 4 + 2] = ai;
        red[wave * 4 + 3] = au;
    }
    __syncthreads();
    if (t == 0) {
        float w = 0.f, bc = 0.f, in = 0.f, un = 0.f;
        #pragma unroll
        for (int i = 0; i < 4; ++i) {
            w  += red[i * 4 + 0];
            bc += red[i * 4 + 1];
            in += red[i * 4 + 2];
            un += red[i * 4 + 3];
        }
        float* o = partials + (size_t)blk * 4;
        o[0] = w; o[1] = bc; o[2] = in; o[3] = un;
    }
}

__global__ __launch_bounds__(256) void structure_loss_finalize(
    const float* __restrict__ partials, float* __restrict__ out)
{
    // partials: [1024][4]; image b owns entries [b*32, (b+1)*32)
    const int t  = threadIdx.x;      // 256 threads
    const int b  = t >> 3;           // image 0..31  (8 threads per image)
    const int i0 = (t & 7) * 4;      // 4 partial-entries per thread
    float w = 0.f, bc = 0.f, in = 0.f, un = 0.f;
    #pragma unroll
    for (int k = 0; k < 4; ++k) {
        float4 v = *(const float4*)(partials + ((size_t)(b * 32 + i0 + k)) * 4);
        w += v.x; bc += v.y; in += v.z; un += v.w;
    }
    #pragma unroll
    for (int off = 4; off > 0; off >>= 1) {
        w  += __shfl_down(w, off);
        bc += __shfl_down(bc, off);
        in += __shfl_down(in, off);
        un += __shfl_down(un, off);
    }
    __shared__ float vals[32];
    if ((t & 7) == 0) {
        float wbce = bc / w;
        float wiou = 1.0f - (in + 1.0f) / (un - in + 1.0f);
        vals[b] = wbce + wiou;
    }
    __syncthreads();
    if (t < 64) {
        float v = (t < 32) ? vals[t] : 0.0f;
        v = wave_reduce(v);
        if (t == 0) out[0] = v / (float)BB;
    }
}

extern "C" void kernel_launch(void* const* d_in, const int* in_sizes, int n_in,
                              void* d_out, int out_size, void* d_ws, size_t ws_size,
                              hipStream_t stream) {
    const float* pred   = (const float*)d_in[0];
    const float* target = (const float*)d_in[1];
    float* out      = (float*)d_out;
    float* partials = (float*)d_ws;   // NBLOCKS*4 floats = 16 KB

    structure_loss_main<<<NBLOCKS, NTHREADS, 0, stream>>>(pred, target, partials);
    structure_loss_finalize<<<1, 256, 0, stream>>>(partials, out);
}

// Round 6
// 110.928 us; speedup vs baseline: 1.1592x; 1.0111x over previous
//
#include <hip/hip_runtime.h>
#include <math.h>

// StructureLoss: B=32, C=1, H=W=512, 31x31 box filter, pad 15
#define BB 32
#define HH 512
#define WW 512
#define KK 31
#define PP 15
#define WROWS 4                       // rows per wave
#define HSEG 16                       // rows per block (4 waves x 4 rows)
#define BLOCKS_PER_IMG (HH / HSEG)    // 32
#define NBLOCKS (BB * BLOCKS_PER_IMG) // 1024 -> 4 blocks/CU, 16 waves/CU
#define NTHREADS 256

__device__ inline float wave_reduce(float v) {
    #pragma unroll
    for (int off = 32; off > 0; off >>= 1) v += __shfl_down(v, off);
    return v;
}

// 3 transcendentals/px: e=exp(-|x|), r=rcp(1+e) -> sigmoid = r or 1-r,
// log1p(e) = -log(r)
__device__ inline void accum_px(float s, float tg, float x,
                                float& aw, float& ab, float& ai, float& au) {
    const float inv = 1.0f / (float)(KK * KK);
    float pooled = s * inv;
    float weit = fmaf(5.0f, fabsf(pooled - tg), 1.0f);
    float e  = __expf(-fabsf(x));
    float rr = __builtin_amdgcn_rcpf(1.0f + e);
    float bce = fmaxf(x, 0.0f) - x * tg - __logf(rr);
    float p  = (x >= 0.0f) ? rr : (1.0f - rr);
    aw += weit;
    ab = fmaf(weit, bce, ab);
    ai = fmaf(p * tg, weit, ai);
    au = fmaf(p + tg, weit, au);
}

__device__ inline float4 ld4(const float* base, int y, int c) {
    return *(const float4*)(base + (size_t)y * WW + c);
}
// row-clamped load, zeroed if row OOB (y is wave-uniform)
__device__ inline float4 ld4z(const float* base, int y, int c) {
    int yc = min(max(y, 0), HH - 1);
    float4 v = *(const float4*)(base + (size_t)yc * WW + c);
    if (y < 0 || y >= HH) v = make_float4(0.f, 0.f, 0.f, 0.f);
    return v;
}

__global__ __launch_bounds__(NTHREADS, 4) void structure_loss_main(
    const float* __restrict__ pred, const float* __restrict__ target,
    float* __restrict__ partials /* [NBLOCKS][4] */)
{
    __shared__ float red[4 * 4];

    const int t   = threadIdx.x;
    const int w   = t >> 6;            // wave 0..3
    const int L   = t & 63;            // lane
    const int blk = blockIdx.x;
    const int b   = blk >> 5;          // image
    const int seg = blk & 31;          // 16-row segment
    const int y0  = seg * HSEG + w * WROWS;   // wave's first row
    const int c0  = 8 * L;             // lane owns cols [c0, c0+8)

    const float* tb = target + (size_t)b * HH * WW;
    const float* pb = pred   + (size_t)b * HH * WW;

    // edge masks for cross-lane halo (exact zero padding at row ends)
    const float m_u1 = (L >= 1) ? 1.f : 0.f;
    const float m_u2 = (L >= 2) ? 1.f : 0.f;
    const float m_d1 = (L <= 62) ? 1.f : 0.f;
    const float m_d2 = (L <= 61) ? 1.f : 0.f;

    // ---- vertical running sums for rows [y0-15, y0+15], 8 cols in regs ----
    float4 vsA = make_float4(0.f,0.f,0.f,0.f);
    float4 vsB = make_float4(0.f,0.f,0.f,0.f);
    if (y0 >= PP && y0 + PP < HH) {            // interior (wave-uniform branch)
        #pragma unroll
        for (int j = -PP; j <= PP; ++j) {
            float4 u = ld4(tb, y0 + j, c0);
            float4 v = ld4(tb, y0 + j, c0 + 4);
            vsA.x += u.x; vsA.y += u.y; vsA.z += u.z; vsA.w += u.w;
            vsB.x += v.x; vsB.y += v.y; vsB.z += v.z; vsB.w += v.w;
        }
    } else {
        #pragma unroll
        for (int j = -PP; j <= PP; ++j) {
            float4 u = ld4z(tb, y0 + j, c0);
            float4 v = ld4z(tb, y0 + j, c0 + 4);
            vsA.x += u.x; vsA.y += u.y; vsA.z += u.z; vsA.w += u.w;
            vsB.x += v.x; vsB.y += v.y; vsB.z += v.z; vsB.w += v.w;
        }
    }

    // prologue prefetch for row y0
    float4 tgA = ld4(tb, y0, c0),  tgB = ld4(tb, y0, c0 + 4);
    float4 prA = ld4(pb, y0, c0),  prB = ld4(pb, y0, c0 + 4);
    float4 adA = ld4z(tb, y0 + PP + 1, c0), adB = ld4z(tb, y0 + PP + 1, c0 + 4);
    float4 sbA = ld4z(tb, y0 - PP, c0),     sbB = ld4z(tb, y0 - PP, c0 + 4);

    float aw = 0.f, ab = 0.f, ai = 0.f, au = 0.f;

    #pragma unroll
    for (int r = 0; r < WROWS; ++r) {
        // prefetch next row (in flight across this row's compute; no barriers)
        float4 tgA2, tgB2, prA2, prB2, adA2, adB2, sbA2, sbB2;
        if (r < WROWS - 1) {
            int y = y0 + r + 1;
            tgA2 = ld4(tb, y, c0);  tgB2 = ld4(tb, y, c0 + 4);
            prA2 = ld4(pb, y, c0);  prB2 = ld4(pb, y, c0 + 4);
            adA2 = ld4z(tb, y + PP + 1, c0); adB2 = ld4z(tb, y + PP + 1, c0 + 4);
            sbA2 = ld4z(tb, y - PP, c0);     sbB2 = ld4z(tb, y - PP, c0 + 4);
        }

        // ---- horizontal 31-window via cross-lane (17 shuffles, no LDS) ----
        float own  = vsA.x + vsA.y + vsA.z + vsA.w + vsB.x + vsB.y + vsB.z + vsB.w;
        float own7 = own - vsA.x;   // neighbor's cols 1..7 when shifted
        // s(c0) = sum cols [c0-15, c0+15]
        float s0 = own
                 + m_u2 * __shfl_up(own7, 2)
                 + m_u1 * __shfl_up(own, 1)
                 + m_d1 * __shfl_down(own, 1);
        // add taps: cols c0+16..c0+22 = lane L+2 elems 0..6
        float a0 = m_d2 * __shfl_down(vsA.x, 2);
        float a1 = m_d2 * __shfl_down(vsA.y, 2);
        float a2 = m_d2 * __shfl_down(vsA.z, 2);
        float a3 = m_d2 * __shfl_down(vsA.w, 2);
        float a4 = m_d2 * __shfl_down(vsB.x, 2);
        float a5 = m_d2 * __shfl_down(vsB.y, 2);
        float a6 = m_d2 * __shfl_down(vsB.z, 2);
        // sub taps: cols c0-15..c0-9 = lane L-2 elems 1..7
        float q0 = m_u2 * __shfl_up(vsA.y, 2);
        float q1 = m_u2 * __shfl_up(vsA.z, 2);
        float q2 = m_u2 * __shfl_up(vsA.w, 2);
        float q3 = m_u2 * __shfl_up(vsB.x, 2);
        float q4 = m_u2 * __shfl_up(vsB.y, 2);
        float q5 = m_u2 * __shfl_up(vsB.z, 2);
        float q6 = m_u2 * __shfl_up(vsB.w, 2);

        float s1 = s0 + a0 - q0;
        float s2 = s1 + a1 - q1;
        float s3 = s2 + a2 - q2;
        float s4 = s3 + a3 - q3;
        float s5 = s4 + a4 - q4;
        float s6 = s5 + a5 - q5;
        float s7 = s6 + a6 - q6;

        accum_px(s0, tgA.x, prA.x, aw, ab, ai, au);
        accum_px(s1, tgA.y, prA.y, aw, ab, ai, au);
        accum_px(s2, tgA.z, prA.z, aw, ab, ai, au);
        accum_px(s3, tgA.w, prA.w, aw, ab, ai, au);
        accum_px(s4, tgB.x, prB.x, aw, ab, ai, au);
        accum_px(s5, tgB.y, prB.y, aw, ab, ai, au);
        accum_px(s6, tgB.z, prB.z, aw, ab, ai, au);
        accum_px(s7, tgB.w, prB.w, aw, ab, ai, au);

        // vertical slide to next row
        vsA.x += adA.x - sbA.x; vsA.y += adA.y - sbA.y;
        vsA.z += adA.z - sbA.z; vsA.w += adA.w - sbA.w;
        vsB.x += adB.x - sbB.x; vsB.y += adB.y - sbB.y;
        vsB.z += adB.z - sbB.z; vsB.w += adB.w - sbB.w;

        tgA = tgA2; tgB = tgB2; prA = prA2; prB = prB2;
        adA = adA2; adB = adB2; sbA = sbA2; sbB = sbB2;
    }

    // block reduction (the only barriers in the kernel, at the very end)
    aw = wave_reduce(aw);
    ab = wave_reduce(ab);
    ai = wave_reduce(ai);
    au = wave_reduce(au);
    if (L == 0) {
        red[w * 4 + 0] = aw;
        red[w * 4 + 1] = ab;
        red[w * 4 + 2] = ai;
        red[w * 4 + 3] = au;
    }
    __syncthreads();
    if (t == 0) {
        float ww = 0.f, bc = 0.f, in = 0.f, un = 0.f;
        #pragma unroll
        for (int i = 0; i < 4; ++i) {
            ww += red[i * 4 + 0];
            bc += red[i * 4 + 1];
            in += red[i * 4 + 2];
            un += red[i * 4 + 3];
        }
        float* o = partials + (size_t)blk * 4;
        o[0] = ww; o[1] = bc; o[2] = in; o[3] = un;
    }
}

__global__ __launch_bounds__(256) void structure_loss_finalize(
    const float* __restrict__ partials, float* __restrict__ out)
{
    // partials: [1024][4]; image b owns entries [b*32, (b+1)*32)
    const int t  = threadIdx.x;      // 256 threads
    const int b  = t >> 3;           // image 0..31  (8 threads per image)
    const int i0 = (t & 7) * 4;      // 4 partial-entries per thread
    float w = 0.f, bc = 0.f, in = 0.f, un = 0.f;
    #pragma unroll
    for (int k = 0; k < 4; ++k) {
        float4 v = *(const float4*)(partials + ((size_t)(b * 32 + i0 + k)) * 4);
        w += v.x; bc += v.y; in += v.z; un += v.w;
    }
    #pragma unroll
    for (int off = 4; off > 0; off >>= 1) {
        w  += __shfl_down(w, off);
        bc += __shfl_down(bc, off);
        in += __shfl_down(in, off);
        un += __shfl_down(un, off);
    }
    __shared__ float vals[32];
    if ((t & 7) == 0) {
        float wbce = bc / w;
        float wiou = 1.0f - (in + 1.0f) / (un - in + 1.0f);
        vals[b] = wbce + wiou;
    }
    __syncthreads();
    if (t < 64) {
        float v = (t < 32) ? vals[t] : 0.0f;
        v = wave_reduce(v);
        if (t == 0) out[0] = v / (float)BB;
    }
}

extern "C" void kernel_launch(void* const* d_in, const int* in_sizes, int n_in,
                              void* d_out, int out_size, void* d_ws, size_t ws_size,
                              hipStream_t stream) {
    const float* pred   = (const float*)d_in[0];
    const float* target = (const float*)d_in[1];
    float* out      = (float*)d_out;
    float* partials = (float*)d_ws;   // NBLOCKS*4 floats = 16 KB

    structure_loss_main<<<NBLOCKS, NTHREADS, 0, stream>>>(pred, target, partials);
    structure_loss_finalize<<<1, 256, 0, stream>>>(partials, out);
}